// Round 1
// baseline (214.186 us; speedup 1.0000x reference)
//
#include <hip/hip_runtime.h>
#include <hip/hip_bf16.h>
#include <stdint.h>

#define NP 30000
#define NV 30000
#define BBINS 80
#define INCH 16
#define OUTCH 32
#define TBINS 16
#define KDIM 1280      // BBINS*INCH
#define NDIM 512       // OUTCH*TBINS
#define KSTEPS 40      // KDIM/32, 2 bins per step

typedef __bf16 bf16x8 __attribute__((ext_vector_type(8)));
typedef float f32x4 __attribute__((ext_vector_type(4)));

__device__ __forceinline__ void async_ld16(const void* g, void* l) {
    __builtin_amdgcn_global_load_lds(
        (const __attribute__((address_space(1))) unsigned int*)g,
        (__attribute__((address_space(3))) unsigned int*)l,
        16, 0, 0);
}

// ---------------------------------------------------------------------------
// Prep: build PW[kc][n][qs][e] bf16, where chunk (kc,n,qs) holds
// lw^T[n][ kc*32 + ((qs ^ (n&3))<<3) + e ],  lw[k][n] = W[(b+5t)%80][c][o],
// k = b*16+c, n = o*16+t.  Pre-swizzled so GEMM's linear global_load_lds
// produces a conflict-free ds_read_b128 B-fragment layout.
// ---------------------------------------------------------------------------
__global__ void prep_weights(const float* __restrict__ w, __bf16* __restrict__ pw) {
    int gid = blockIdx.x * 256 + threadIdx.x;           // 40*512*32 = 655360 total
    int e  = gid & 7;
    int qs = (gid >> 3) & 3;
    int n  = (gid >> 5) & 511;
    int kc = gid >> 14;                                  // 0..39
    int kp = kc * 32 + ((qs ^ (n & 3)) << 3) + e;        // 0..1279
    int b = kp >> 4, c = kp & 15;
    int o = n >> 4,  t = n & 15;
    int bid = (b + 5 * t) % BBINS;
    pw[gid] = (__bf16)w[(bid * INCH + c) * OUTCH + o];
}

// ---------------------------------------------------------------------------
// Fused gather + GEMM + max-over-t.
// Block: 512 threads (8 waves), M_BLOCK=128 patches, N=512 (all of out*t).
// Wave (mrow=wave>>2, ncol=wave&3) computes 64x128 via 4x8 tiles of
// mfma_f32_16x16x32_bf16.
// ---------------------------------------------------------------------------
__global__ __launch_bounds__(512, 2) void geo_main(
    const float* __restrict__ x,
    const int*   __restrict__ cidx,
    const float* __restrict__ cval,
    const __bf16* __restrict__ pw,
    float* __restrict__ out) {

    // A: 128 rows x 32 bf16, padded row stride 40 bf16 (80 B) -> uniform banks
    __shared__ __align__(16) __bf16 Alds[128 * 40];      // 10240 B
    // B: verbatim 32 KB K-slice of PW (n-major, 64 B per n, chunk-swizzled)
    __shared__ __align__(16) __bf16 Blds[32 * 512];      // 32768 B

    const int tid  = threadIdx.x;
    const int lane = tid & 63;
    const int wave = tid >> 6;
    const int wave_mrow = wave >> 2;     // 0..1
    const int wave_ncol = wave & 3;      // 0..3
    const int nbase = blockIdx.x * 128;

    // Fragment LDS byte offsets — constant across the K loop.
    int a_off[4], b_off[8];
    {
        const int ml = lane & 15, q = lane >> 4;
#pragma unroll
        for (int i = 0; i < 4; ++i)
            a_off[i] = (wave_mrow * 64 + i * 16 + ml) * 80 + q * 16;
#pragma unroll
        for (int j = 0; j < 8; ++j) {
            int n = wave_ncol * 128 + j * 16 + ml;
            b_off[j] = n * 64 + ((q ^ (n & 3)) << 4);
        }
    }

    f32x4 acc[4][8];
#pragma unroll
    for (int i = 0; i < 4; ++i)
#pragma unroll
        for (int j = 0; j < 8; ++j)
            acc[i][j] = (f32x4){0.f, 0.f, 0.f, 0.f};

    // Gather role: threads 0..255, one (patch, bin) row each, all 16 channels.
    const int gm = tid >> 1;             // row within block (0..127)
    const int gb = tid & 1;              // which of the 2 bins this K-step
    const int patch = nbase + gm;
    const bool gact = (tid < 256) && (patch < NP);

    const char* pwB = (const char*)pw;

    for (int kc = 0; kc < KSTEPS; ++kc) {
        // ---- stage B: async global->LDS, 512 threads x 4 chunks of 16 B
        {
            const char* src = pwB + kc * 32768 + tid * 16;
            char* dst = (char*)Blds + tid * 16;
#pragma unroll
            for (int t = 0; t < 4; ++t)
                async_ld16(src + t * 8192, dst + t * 8192);
        }
        // ---- gather A rows
        if (tid < 256) {
            float h[16];
#pragma unroll
            for (int c = 0; c < 16; ++c) h[c] = 0.f;
            if (gact) {
                const int r3 = (patch * 80 + (kc * 2 + gb)) * 3;
                const int i0 = cidx[r3 + 0], i1 = cidx[r3 + 1], i2 = cidx[r3 + 2];
                const float v0 = cval[r3 + 0], v1 = cval[r3 + 1], v2 = cval[r3 + 2];
                const float4* xp0 = (const float4*)(x + (size_t)i0 * 16);
                const float4* xp1 = (const float4*)(x + (size_t)i1 * 16);
                const float4* xp2 = (const float4*)(x + (size_t)i2 * 16);
#pragma unroll
                for (int p = 0; p < 4; ++p) {
                    float4 a = xp0[p], b = xp1[p], c = xp2[p];
                    h[p * 4 + 0] = v0 * a.x + v1 * b.x + v2 * c.x;
                    h[p * 4 + 1] = v0 * a.y + v1 * b.y + v2 * c.y;
                    h[p * 4 + 2] = v0 * a.z + v1 * b.z + v2 * c.z;
                    h[p * 4 + 3] = v0 * a.w + v1 * b.w + v2 * c.w;
                }
            }
            bf16x8 lo, hi;
#pragma unroll
            for (int c = 0; c < 8; ++c) {
                lo[c] = (__bf16)h[c];
                hi[c] = (__bf16)h[c + 8];
            }
            char* wp = (char*)Alds + gm * 80 + gb * 32;
            *(bf16x8*)(wp)      = lo;
            *(bf16x8*)(wp + 16) = hi;
        }
        __syncthreads();   // drains global_load_lds (vmcnt) + ds_writes (lgkm)

        // ---- MFMA
        bf16x8 af[4], bfr[8];
#pragma unroll
        for (int i = 0; i < 4; ++i)
            af[i] = *(const bf16x8*)((const char*)Alds + a_off[i]);
#pragma unroll
        for (int j = 0; j < 8; ++j)
            bfr[j] = *(const bf16x8*)((const char*)Blds + b_off[j]);
#pragma unroll
        for (int i = 0; i < 4; ++i)
#pragma unroll
            for (int j = 0; j < 8; ++j)
                acc[i][j] = __builtin_amdgcn_mfma_f32_16x16x32_bf16(
                    af[i], bfr[j], acc[i][j], 0, 0, 0);
        __syncthreads();   // protect LDS tiles from next iteration's overwrite
    }

    // ---- epilogue: max over t (t = col = lane&15 within each 16-col group)
    const int rgrp = lane >> 4;
    const int tl   = lane & 15;
#pragma unroll
    for (int i = 0; i < 4; ++i) {
#pragma unroll
        for (int j = 0; j < 8; ++j) {
            float v0 = acc[i][j][0], v1 = acc[i][j][1];
            float v2 = acc[i][j][2], v3 = acc[i][j][3];
#pragma unroll
            for (int off = 1; off < 16; off <<= 1) {
                v0 = fmaxf(v0, __shfl_xor(v0, off));
                v1 = fmaxf(v1, __shfl_xor(v1, off));
                v2 = fmaxf(v2, __shfl_xor(v2, off));
                v3 = fmaxf(v3, __shfl_xor(v3, off));
            }
            if (tl == 0) {
                const int o  = wave_ncol * 8 + j;
                const int pr = nbase + wave_mrow * 64 + i * 16 + rgrp * 4;
                if (pr + 0 < NP) out[(pr + 0) * 32 + o] = v0;
                if (pr + 1 < NP) out[(pr + 1) * 32 + o] = v1;
                if (pr + 2 < NP) out[(pr + 2) * 32 + o] = v2;
                if (pr + 3 < NP) out[(pr + 3) * 32 + o] = v3;
            }
        }
    }
}

extern "C" void kernel_launch(void* const* d_in, const int* in_sizes, int n_in,
                              void* d_out, int out_size, void* d_ws, size_t ws_size,
                              hipStream_t stream) {
    const float* x    = (const float*)d_in[0];
    const int*   cidx = (const int*)d_in[1];
    const float* cval = (const float*)d_in[2];
    const float* w    = (const float*)d_in[3];
    float* out = (float*)d_out;
    __bf16* pw = (__bf16*)d_ws;   // 655360 bf16 = 1.25 MB scratch

    // Rebuild PW every call (d_ws is re-poisoned before each timed launch).
    hipLaunchKernelGGL(prep_weights, dim3(2560), dim3(256), 0, stream, w, pw);
    hipLaunchKernelGGL(geo_main, dim3((NP + 127) / 128), dim3(512), 0, stream,
                       x, cidx, cval, (const __bf16*)pw, out);
}

// Round 2
// 202.640 us; speedup vs baseline: 1.0570x; 1.0570x over previous
//
#include <hip/hip_runtime.h>
#include <hip/hip_bf16.h>
#include <stdint.h>

#define NP 30000
#define BBINS 80
#define INCH 16
#define OUTCH 32
#define KDIM 1280       // BBINS*INCH
#define NDIM 512        // OUTCH*TBINS
#define KSTEPS 40       // KDIM/32
#define NROWS (NP * BBINS)   // 2,400,000

typedef __bf16 bf16x8 __attribute__((ext_vector_type(8)));
typedef float f32x4 __attribute__((ext_vector_type(4)));

__device__ __forceinline__ void async_ld16(const void* g, void* l) {
    __builtin_amdgcn_global_load_lds(
        (const __attribute__((address_space(1))) unsigned int*)g,
        (__attribute__((address_space(3))) unsigned int*)l,
        16, 0, 0);
}

// ---------------------------------------------------------------------------
// Prep: PW[kc][n][qs][e] bf16 with chunk-XOR swizzle (qs ^ (n&3)), where
// lw[k][n] = W[(b+5t)%80][c][o], k=b*16+c, n=o*16+t.
// ---------------------------------------------------------------------------
__global__ void prep_weights(const float* __restrict__ w, __bf16* __restrict__ pw) {
    int gid = blockIdx.x * 256 + threadIdx.x;           // 655360 total
    int e  = gid & 7;
    int qs = (gid >> 3) & 3;
    int n  = (gid >> 5) & 511;
    int kc = gid >> 14;                                  // 0..39
    int kp = kc * 32 + ((qs ^ (n & 3)) << 3) + e;        // 0..1279
    int b = kp >> 4, c = kp & 15;
    int o = n >> 4,  t = n & 15;
    int bid = (b + 5 * t) % BBINS;
    pw[gid] = (__bf16)w[(bid * INCH + c) * OUTCH + o];
}

// ---------------------------------------------------------------------------
// Gather: one thread per (patch,bin) row. h[r][c] = sum_k val[r][k]*x[idx[r][k]][c]
// Fully parallel, no barriers — latency hidden by TLP.
// ---------------------------------------------------------------------------
__global__ __launch_bounds__(256) void gather_h(
    const float* __restrict__ x,
    const int*   __restrict__ cidx,
    const float* __restrict__ cval,
    __bf16* __restrict__ h) {
    const int r = blockIdx.x * 256 + threadIdx.x;        // NROWS = 9375*256 exact
    const int r3 = r * 3;
    const int i0 = cidx[r3 + 0], i1 = cidx[r3 + 1], i2 = cidx[r3 + 2];
    const float v0 = cval[r3 + 0], v1 = cval[r3 + 1], v2 = cval[r3 + 2];
    const float4* xp0 = (const float4*)(x + (size_t)i0 * 16);
    const float4* xp1 = (const float4*)(x + (size_t)i1 * 16);
    const float4* xp2 = (const float4*)(x + (size_t)i2 * 16);
    float hh[16];
#pragma unroll
    for (int p = 0; p < 4; ++p) {
        float4 a = xp0[p], b = xp1[p], c = xp2[p];
        hh[p * 4 + 0] = v0 * a.x + v1 * b.x + v2 * c.x;
        hh[p * 4 + 1] = v0 * a.y + v1 * b.y + v2 * c.y;
        hh[p * 4 + 2] = v0 * a.z + v1 * b.z + v2 * c.z;
        hh[p * 4 + 3] = v0 * a.w + v1 * b.w + v2 * c.w;
    }
    bf16x8 lo, hi;
#pragma unroll
    for (int c = 0; c < 8; ++c) { lo[c] = (__bf16)hh[c]; hi[c] = (__bf16)hh[c + 8]; }
    char* wp = (char*)h + (size_t)r * 32;
    *(bf16x8*)(wp)      = lo;
    *(bf16x8*)(wp + 16) = hi;
}

// ---------------------------------------------------------------------------
// GEMM + max-over-t.  Block: 256 threads (4 waves), tile 128 rows x 256 cols.
// Wave grid 2x2; wave tile 64x128 = 4x8 mfma_f32_16x16x32_bf16.
// Grid 480 with XCD-paired swizzle: (m,ncol=0) and (m,ncol=1) land on the
// same XCD so the h row-block is HBM-fetched once, L2-hit the second time.
// ---------------------------------------------------------------------------
__global__ __launch_bounds__(256, 2) void gemm_max(
    const __bf16* __restrict__ h,
    const __bf16* __restrict__ pw,
    float* __restrict__ out) {

    __shared__ __align__(16) __bf16 Alds[128 * 32];      // 8 KB  (row stride 64 B)
    __shared__ __align__(16) __bf16 Blds[256 * 32];      // 16 KB (n stride 64 B)

    const int bid = blockIdx.x;
    const int m    = (bid >> 4) * 8 + (bid & 7);         // 0..239
    const int ncol = (bid >> 3) & 1;                     // 0/1
    if (m >= 235) return;                                // 10 dead pad blocks
    const int mbase = m * 128;

    const int tid  = threadIdx.x;
    const int lane = tid & 63;
    const int wave = tid >> 6;
    const int wave_mrow = wave >> 1;     // 0..1
    const int wave_ncol = wave & 1;      // 0..1

    // Fragment LDS byte offsets
    int a_off[4], b_off[8];
    {
        const int ml = lane & 15, q = lane >> 4;
#pragma unroll
        for (int i = 0; i < 4; ++i)
            a_off[i] = (wave_mrow * 64 + i * 16 + ml) * 64 + q * 16;
#pragma unroll
        for (int j = 0; j < 8; ++j) {
            int nl = wave_ncol * 128 + j * 16 + ml;
            b_off[j] = nl * 64 + ((q ^ (nl & 3)) << 4);
        }
    }

    f32x4 acc[4][8];
#pragma unroll
    for (int i = 0; i < 4; ++i)
#pragma unroll
        for (int j = 0; j < 8; ++j)
            acc[i][j] = (f32x4){0.f, 0.f, 0.f, 0.f};

    // Staging source pointers (kc-invariant parts)
    const char* hB  = (const char*)h;
    const char* pwB = (const char*)pw + ncol * 16384 + tid * 16;
    int rg0 = mbase + (tid >> 2);        // rows 0..63 of tile
    int rg1 = rg0 + 64;                  // rows 64..127
    if (rg0 > NP - 1) rg0 = NP - 1;      // clamp (values unused, guarded in epilogue)
    if (rg1 > NP - 1) rg1 = NP - 1;
    const char* aSrc0 = hB + (size_t)rg0 * 2560 + (tid & 3) * 16;
    const char* aSrc1 = hB + (size_t)rg1 * 2560 + (tid & 3) * 16;
    char* aDst0 = (char*)Alds + tid * 16;
    char* aDst1 = aDst0 + 4096;
    char* bDst  = (char*)Blds + tid * 16;

    for (int kc = 0; kc < KSTEPS; ++kc) {
        // ---- stage B (16 KB) + A (8 KB) via async global->LDS
        const char* bs = pwB + kc * 32768;
#pragma unroll
        for (int i = 0; i < 4; ++i)
            async_ld16(bs + i * 4096, bDst + i * 4096);
        async_ld16(aSrc0 + kc * 64, aDst0);
        async_ld16(aSrc1 + kc * 64, aDst1);
        __syncthreads();

        // ---- MFMA
        bf16x8 af[4], bfr[8];
#pragma unroll
        for (int i = 0; i < 4; ++i)
            af[i] = *(const bf16x8*)((const char*)Alds + a_off[i]);
#pragma unroll
        for (int j = 0; j < 8; ++j)
            bfr[j] = *(const bf16x8*)((const char*)Blds + b_off[j]);
#pragma unroll
        for (int i = 0; i < 4; ++i)
#pragma unroll
            for (int j = 0; j < 8; ++j)
                acc[i][j] = __builtin_amdgcn_mfma_f32_16x16x32_bf16(
                    af[i], bfr[j], acc[i][j], 0, 0, 0);
        __syncthreads();
    }

    // ---- epilogue: max over t (t = col = lane&15), store o = n>>4
    const int rgrp = lane >> 4;
    const int tl   = lane & 15;
#pragma unroll
    for (int i = 0; i < 4; ++i) {
#pragma unroll
        for (int j = 0; j < 8; ++j) {
            float v0 = acc[i][j][0], v1 = acc[i][j][1];
            float v2 = acc[i][j][2], v3 = acc[i][j][3];
#pragma unroll
            for (int off = 1; off < 16; off <<= 1) {
                v0 = fmaxf(v0, __shfl_xor(v0, off));
                v1 = fmaxf(v1, __shfl_xor(v1, off));
                v2 = fmaxf(v2, __shfl_xor(v2, off));
                v3 = fmaxf(v3, __shfl_xor(v3, off));
            }
            if (tl == 0) {
                const int o  = ncol * 16 + wave_ncol * 8 + j;
                const int pr = mbase + wave_mrow * 64 + i * 16 + rgrp * 4;
                if (pr + 0 < NP) out[(pr + 0) * 32 + o] = v0;
                if (pr + 1 < NP) out[(pr + 1) * 32 + o] = v1;
                if (pr + 2 < NP) out[(pr + 2) * 32 + o] = v2;
                if (pr + 3 < NP) out[(pr + 3) * 32 + o] = v3;
            }
        }
    }
}

extern "C" void kernel_launch(void* const* d_in, const int* in_sizes, int n_in,
                              void* d_out, int out_size, void* d_ws, size_t ws_size,
                              hipStream_t stream) {
    const float* x    = (const float*)d_in[0];
    const int*   cidx = (const int*)d_in[1];
    const float* cval = (const float*)d_in[2];
    const float* w    = (const float*)d_in[3];
    float* out = (float*)d_out;

    __bf16* pw = (__bf16*)d_ws;                               // 1.31 MB
    __bf16* h  = (__bf16*)((char*)d_ws + (2 << 20));          // 76.8 MB @ +2MB

    hipLaunchKernelGGL(prep_weights, dim3(2560), dim3(256), 0, stream, w, pw);
    hipLaunchKernelGGL(gather_h, dim3(NROWS / 256), dim3(256), 0, stream,
                       x, cidx, cval, h);
    hipLaunchKernelGGL(gemm_max, dim3(480), dim3(256), 0, stream,
                       h, (const __bf16*)pw, out);
}

// Round 3
// 188.847 us; speedup vs baseline: 1.1342x; 1.0730x over previous
//
#include <hip/hip_runtime.h>
#include <hip/hip_bf16.h>
#include <stdint.h>

#define NP 30000
#define BBINS 80
#define INCH 16
#define OUTCH 32
#define KDIM 1280       // BBINS*INCH
#define NDIM 512        // OUTCH*TBINS
#define KSTEPS 40       // KDIM/32
#define NROWS (NP * BBINS)   // 2,400,000

typedef __bf16 bf16x8 __attribute__((ext_vector_type(8)));
typedef __bf16 bf16x4 __attribute__((ext_vector_type(4)));
typedef float f32x4 __attribute__((ext_vector_type(4)));

__device__ __forceinline__ void async_ld16(const void* g, void* l) {
    __builtin_amdgcn_global_load_lds(
        (const __attribute__((address_space(1))) unsigned int*)g,
        (__attribute__((address_space(3))) unsigned int*)l,
        16, 0, 0);
}

// ---------------------------------------------------------------------------
// Prep: PW[kc][n][qs][e] bf16 with chunk-XOR swizzle (qs ^ (n&3)), where
// lw[k][n] = W[(b+5t)%80][c][o], k=b*16+c, n=o*16+t.
// ---------------------------------------------------------------------------
__global__ void prep_weights(const float* __restrict__ w, __bf16* __restrict__ pw) {
    int gid = blockIdx.x * 256 + threadIdx.x;           // 655360 total
    int e  = gid & 7;
    int qs = (gid >> 3) & 3;
    int n  = (gid >> 5) & 511;
    int kc = gid >> 14;                                  // 0..39
    int kp = kc * 32 + ((qs ^ (n & 3)) << 3) + e;        // 0..1279
    int b = kp >> 4, c = kp & 15;
    int o = n >> 4,  t = n & 15;
    int bid = (b + 5 * t) % BBINS;
    pw[gid] = (__bf16)w[(bid * INCH + c) * OUTCH + o];
}

// ---------------------------------------------------------------------------
// Gather: FOUR lanes per (patch,bin) row; lane-quad member q loads channels
// [4q,4q+4) of each of the 3 support rows. Per x-load instruction a wave
// covers 16 distinct 64-B lines (4 contiguous lanes each) instead of 64 —
// 16x fewer L1 transactions than one-thread-per-row.
// ---------------------------------------------------------------------------
__global__ __launch_bounds__(256) void gather_h(
    const float* __restrict__ x,
    const int*   __restrict__ cidx,
    const float* __restrict__ cval,
    __bf16* __restrict__ h) {
    const int gid = blockIdx.x * 256 + threadIdx.x;      // 9,600,000 total
    const int r = gid >> 2;                              // row 0..NROWS-1
    const int q = gid & 3;                               // channel quad
    const int r3 = r * 3;
    const int i0 = cidx[r3 + 0], i1 = cidx[r3 + 1], i2 = cidx[r3 + 2];
    const float v0 = cval[r3 + 0], v1 = cval[r3 + 1], v2 = cval[r3 + 2];
    const float4 a = *(const float4*)(x + (size_t)i0 * 16 + q * 4);
    const float4 b = *(const float4*)(x + (size_t)i1 * 16 + q * 4);
    const float4 c = *(const float4*)(x + (size_t)i2 * 16 + q * 4);
    bf16x4 hv;
    hv[0] = (__bf16)(v0 * a.x + v1 * b.x + v2 * c.x);
    hv[1] = (__bf16)(v0 * a.y + v1 * b.y + v2 * c.y);
    hv[2] = (__bf16)(v0 * a.z + v1 * b.z + v2 * c.z);
    hv[3] = (__bf16)(v0 * a.w + v1 * b.w + v2 * c.w);
    *(bf16x4*)((char*)h + (size_t)gid * 8) = hv;
}

// ---------------------------------------------------------------------------
// GEMM + max-over-t.  Block: 256 threads (4 waves), tile 128 rows x 256 cols.
// Wave grid 2x2; wave tile 64x128 = 4x8 mfma_f32_16x16x32_bf16.
// ---------------------------------------------------------------------------
__global__ __launch_bounds__(256, 2) void gemm_max(
    const __bf16* __restrict__ h,
    const __bf16* __restrict__ pw,
    float* __restrict__ out) {

    __shared__ __align__(16) __bf16 Alds[128 * 32];      // 8 KB  (row stride 64 B)
    __shared__ __align__(16) __bf16 Blds[256 * 32];      // 16 KB (n stride 64 B)

    const int bid = blockIdx.x;
    const int m    = (bid >> 4) * 8 + (bid & 7);         // 0..239
    const int ncol = (bid >> 3) & 1;                     // 0/1
    if (m >= 235) return;                                // 10 dead pad blocks
    const int mbase = m * 128;

    const int tid  = threadIdx.x;
    const int lane = tid & 63;
    const int wave = tid >> 6;
    const int wave_mrow = wave >> 1;     // 0..1
    const int wave_ncol = wave & 1;      // 0..1

    int a_off[4], b_off[8];
    {
        const int ml = lane & 15, q = lane >> 4;
#pragma unroll
        for (int i = 0; i < 4; ++i)
            a_off[i] = (wave_mrow * 64 + i * 16 + ml) * 64 + q * 16;
#pragma unroll
        for (int j = 0; j < 8; ++j) {
            int nl = wave_ncol * 128 + j * 16 + ml;
            b_off[j] = nl * 64 + ((q ^ (nl & 3)) << 4);
        }
    }

    f32x4 acc[4][8];
#pragma unroll
    for (int i = 0; i < 4; ++i)
#pragma unroll
        for (int j = 0; j < 8; ++j)
            acc[i][j] = (f32x4){0.f, 0.f, 0.f, 0.f};

    const char* hB  = (const char*)h;
    const char* pwB = (const char*)pw + ncol * 16384 + tid * 16;
    int rg0 = mbase + (tid >> 2);        // rows 0..63 of tile
    int rg1 = rg0 + 64;                  // rows 64..127
    if (rg0 > NP - 1) rg0 = NP - 1;
    if (rg1 > NP - 1) rg1 = NP - 1;
    const char* aSrc0 = hB + (size_t)rg0 * 2560 + (tid & 3) * 16;
    const char* aSrc1 = hB + (size_t)rg1 * 2560 + (tid & 3) * 16;
    char* aDst0 = (char*)Alds + tid * 16;
    char* aDst1 = aDst0 + 4096;
    char* bDst  = (char*)Blds + tid * 16;

    for (int kc = 0; kc < KSTEPS; ++kc) {
        const char* bs = pwB + kc * 32768;
#pragma unroll
        for (int i = 0; i < 4; ++i)
            async_ld16(bs + i * 4096, bDst + i * 4096);
        async_ld16(aSrc0 + kc * 64, aDst0);
        async_ld16(aSrc1 + kc * 64, aDst1);
        __syncthreads();

        bf16x8 af[4], bfr[8];
#pragma unroll
        for (int i = 0; i < 4; ++i)
            af[i] = *(const bf16x8*)((const char*)Alds + a_off[i]);
#pragma unroll
        for (int j = 0; j < 8; ++j)
            bfr[j] = *(const bf16x8*)((const char*)Blds + b_off[j]);
#pragma unroll
        for (int i = 0; i < 4; ++i)
#pragma unroll
            for (int j = 0; j < 8; ++j)
                acc[i][j] = __builtin_amdgcn_mfma_f32_16x16x32_bf16(
                    af[i], bfr[j], acc[i][j], 0, 0, 0);
        __syncthreads();
    }

    const int rgrp = lane >> 4;
    const int tl   = lane & 15;
#pragma unroll
    for (int i = 0; i < 4; ++i) {
#pragma unroll
        for (int j = 0; j < 8; ++j) {
            float v0 = acc[i][j][0], v1 = acc[i][j][1];
            float v2 = acc[i][j][2], v3 = acc[i][j][3];
#pragma unroll
            for (int off = 1; off < 16; off <<= 1) {
                v0 = fmaxf(v0, __shfl_xor(v0, off));
                v1 = fmaxf(v1, __shfl_xor(v1, off));
                v2 = fmaxf(v2, __shfl_xor(v2, off));
                v3 = fmaxf(v3, __shfl_xor(v3, off));
            }
            if (tl == 0) {
                const int o  = ncol * 16 + wave_ncol * 8 + j;
                const int pr = mbase + wave_mrow * 64 + i * 16 + rgrp * 4;
                if (pr + 0 < NP) out[(pr + 0) * 32 + o] = v0;
                if (pr + 1 < NP) out[(pr + 1) * 32 + o] = v1;
                if (pr + 2 < NP) out[(pr + 2) * 32 + o] = v2;
                if (pr + 3 < NP) out[(pr + 3) * 32 + o] = v3;
            }
        }
    }
}

extern "C" void kernel_launch(void* const* d_in, const int* in_sizes, int n_in,
                              void* d_out, int out_size, void* d_ws, size_t ws_size,
                              hipStream_t stream) {
    const float* x    = (const float*)d_in[0];
    const int*   cidx = (const int*)d_in[1];
    const float* cval = (const float*)d_in[2];
    const float* w    = (const float*)d_in[3];
    float* out = (float*)d_out;

    __bf16* pw = (__bf16*)d_ws;                               // 1.31 MB
    __bf16* h  = (__bf16*)((char*)d_ws + (2 << 20));          // 76.8 MB @ +2MB

    hipLaunchKernelGGL(prep_weights, dim3(2560), dim3(256), 0, stream, w, pw);
    hipLaunchKernelGGL(gather_h, dim3(NROWS * 4 / 256), dim3(256), 0, stream,
                       x, cidx, cval, h);
    hipLaunchKernelGGL(gemm_max, dim3(480), dim3(256), 0, stream,
                       h, (const __bf16*)pw, out);
}